// Round 7
// baseline (219.787 us; speedup 1.0000x reference)
//
#include <hip/hip_runtime.h>
#include <math.h>

#define KK 8
#define EPSF 1e-9f

typedef unsigned int   uint32;
typedef unsigned short u16;
typedef __attribute__((ext_vector_type(8))) short bf16x8;
typedef __attribute__((ext_vector_type(4))) float f32x4;

#define MFMA_16x16x32(a, b, c) __builtin_amdgcn_mfma_f32_16x16x32_bf16(a, b, c, 0, 0, 0)

typedef __attribute__((address_space(1))) const unsigned int glob_cu32;
typedef __attribute__((address_space(3))) unsigned int lds_u32;
// async global->LDS DMA, 16B per lane; LDS dest = wave-uniform base + lane*16
__device__ __forceinline__ void g2l16(const void* gsrc, void* ldst) {
    __builtin_amdgcn_global_load_lds((glob_cu32*)gsrc, (lds_u32*)ldst, 16, 0, 0);
}

// swizzled ushort index of logical octet o (8 bf16) in a [row][64] LDS tile
__device__ __forceinline__ int swz(int row, int o) {
    return (row << 6) + (((o) ^ (row & 7)) << 3);
}

__device__ __forceinline__ float softplusf(float x) {
    return x > 0.0f ? x + log1pf(expf(-x)) : log1pf(expf(x));
}
__device__ __forceinline__ float sigmoidf_(float x) {
    return 1.0f / (1.0f + expf(-x));
}
// fp32 -> bf16 round-to-nearest-even
__device__ __forceinline__ u16 f2bf(float f) {
    union { float f; uint32 u; } v; v.f = f;
    uint32 u = v.u;
    return (u16)((u + 0x7FFFu + ((u >> 16) & 1u)) >> 16);
}
__device__ __forceinline__ uint32 pack2(float a, float b) {
    return (uint32)f2bf(a) | ((uint32)f2bf(b) << 16);
}

// ---------------------------------------------------------------------------
// prep: V->VT0 bf16 [16][64][512] (transposed), gc_w0->Wt0 bf16 [128][576],
//       gc_w1->Wt1 bf16 [256][1152].
// ---------------------------------------------------------------------------
__global__ __launch_bounds__(256)
void prep_kernel(const float* __restrict__ V, const float* __restrict__ W0,
                 const float* __restrict__ W1, u16* __restrict__ VT0,
                 u16* __restrict__ Wt0, u16* __restrict__ Wt1) {
    __shared__ float s[64][65];
    int blk = blockIdx.x, tid = threadIdx.x;
    if (blk < 128) {            // V [16][512][64] -> VT0 [16][64][512]
        int b = blk >> 3, rt = blk & 7;
#pragma unroll
        for (int t = 0; t < 16; t++) {
            int idx = t * 256 + tid; int r = idx >> 6, c = idx & 63;
            s[r][c] = V[((size_t)b * 512 + rt * 64 + r) * 64 + c];
        }
        __syncthreads();
#pragma unroll
        for (int t = 0; t < 16; t++) {
            int idx = t * 256 + tid; int f = idx >> 6, j = idx & 63;
            VT0[((size_t)b * 64 + f) * 512 + rt * 64 + j] = f2bf(s[j][f]);
        }
    } else if (blk < 146) {     // W0 [576][128] -> Wt0 [128][576]
        int t0 = blk - 128; int rt = t0 >> 1, ct = t0 & 1;
#pragma unroll
        for (int t = 0; t < 16; t++) {
            int idx = t * 256 + tid; int r = idx >> 6, c = idx & 63;
            s[r][c] = W0[((size_t)rt * 64 + r) * 128 + ct * 64 + c];
        }
        __syncthreads();
#pragma unroll
        for (int t = 0; t < 16; t++) {
            int idx = t * 256 + tid; int f = idx >> 6, j = idx & 63;
            Wt0[((size_t)ct * 64 + f) * 576 + rt * 64 + j] = f2bf(s[j][f]);
        }
    } else {                    // W1 [1152][256] -> Wt1 [256][1152]
        int t0 = blk - 146; int rt = t0 >> 2, ct = t0 & 3;
#pragma unroll
        for (int t = 0; t < 16; t++) {
            int idx = t * 256 + tid; int r = idx >> 6, c = idx & 63;
            s[r][c] = W1[((size_t)rt * 64 + r) * 256 + ct * 64 + c];
        }
        __syncthreads();
#pragma unroll
        for (int t = 0; t < 16; t++) {
            int idx = t * 256 + tid; int f = idx >> 6, j = idx & 63;
            Wt1[((size_t)ct * 64 + f) * 1152 + rt * 64 + j] = f2bf(s[j][f]);
        }
    }
}

// ---------------------------------------------------------------------------
// layer0_fused: 16 node-rows/block. Grid 512 = 16 b x 32 tiles. LDS ~43 KB.
//   A: uw row-proj, ci, V->s_X[:, :64]
//   B: j-loop (8x64): packed A-gen -> s_A (b64 stores), DMA V^T, msg MFMA
//   C: acc -> s_X[:, 64:576]
//   D: barrier-free mini-GEMM: W frags DIRECT FROM GLOBAL (b128/lane), X from LDS
//   E: tanh/bn/pool -> H0p fp32 + VT1 bf16 (transposed)
// ---------------------------------------------------------------------------
__global__ __launch_bounds__(256)
void layer0_fused(const u16* __restrict__ VT0, const float* __restrict__ C,
                  const float* __restrict__ V,
                  const float* __restrict__ gw, const float* __restrict__ gb,
                  const float* __restrict__ aw, const float* __restrict__ ab,
                  const u16* __restrict__ Wt0, const float* __restrict__ bias,
                  const float* __restrict__ bng, const float* __restrict__ bnb,
                  float* __restrict__ H0p, u16* __restrict__ VT1) {
    int b = blockIdx.x >> 5, tile = blockIdx.x & 31;
    int i0 = tile * 16;
    int tid = threadIdx.x;
    int wv = tid >> 6, lane = tid & 63, quad = lane >> 4, l15 = lane & 15;

    __shared__ __align__(16) u16 s_mem[12288];   // s_vT 4096 | s_A 8192
    __shared__ __align__(16) u16 s_X[16 * 584];  // 18.7 KB, stride 584
    __shared__ __align__(16) float s_ci[16][4];
    __shared__ float s_u[16][KK];
    __shared__ float s_w[16][KK];

    u16* s_vT = s_mem;
    u16* s_A  = s_mem + 4096;

    // ---- phase A ----
    {
        int t = tid & 127;
        int i = t >> 3, k = t & 7;
        const float4* xr = (const float4*)(V + ((size_t)b * 512 + i0 + i) * 64);
        const float* wm = (tid < 128) ? gw : aw;
        float s = 0.f;
#pragma unroll
        for (int f4 = 0; f4 < 16; f4++) {
            float4 x = xr[f4];
            s += x.x * wm[(f4 * 4 + 0) * 8 + k] + x.y * wm[(f4 * 4 + 1) * 8 + k]
               + x.z * wm[(f4 * 4 + 2) * 8 + k] + x.w * wm[(f4 * 4 + 3) * 8 + k];
        }
        if (tid < 128) s_u[i][k] = softplusf(s + gb[k]);
        else           s_w[i][k] = sigmoidf_(s + ab[k]);
    }
    if (tid < 16) {
        const float* cp = C + ((size_t)b * 512 + i0 + tid) * 3;
        float x = cp[0], y = cp[1], z = cp[2];
        s_ci[tid][0] = x; s_ci[tid][1] = y; s_ci[tid][2] = z;
        s_ci[tid][3] = x * x + y * y + z * z;
    }
    {   // V rows -> s_X cols 0..63 (bf16)
        int row = tid >> 4, f4 = tid & 15;
        float4 x = *(const float4*)(V + ((size_t)b * 512 + i0 + row) * 64 + f4 * 4);
        *(uint32*)&s_X[row * 584 + f4 * 4]     = pack2(x.x, x.y);
        *(uint32*)&s_X[row * 584 + f4 * 4 + 2] = pack2(x.z, x.w);
    }

    // A-gen thread mapping: i = tid>>4 (16), jg = tid&15 (4-j group)
    int ia = tid >> 4, jg = tid & 15;
    int oct = jg >> 1, half = (jg & 1) << 2;

    // ---- phase B: msg K-loop ----
    f32x4 acc[2][4] = {};
    for (int j0 = 0; j0 < 512; j0 += 64) {
        // this thread's 4 j-coords (12 consecutive floats = 3 float4)
        const float4* cp4 = (const float4*)(C + ((size_t)b * 512 + j0 + jg * 4) * 3);
        float4 q0 = cp4[0], q1 = cp4[1], q2 = cp4[2];
        float jx[4] = {q0.x, q0.w, q1.z, q2.y};
        float jy[4] = {q0.y, q1.x, q1.w, q2.z};
        float jz[4] = {q0.z, q1.y, q2.x, q2.w};
        __syncthreads();               // prev-iter LDS reads drained
#pragma unroll
        for (int p = 0; p < 2; p++) {  // DMA V^T tile [64 f][64 j]
            int s = p * 256 + wv * 64 + lane;
            int f = s >> 3, op = s & 7;
            g2l16(VT0 + ((size_t)b * 64 + f) * 512 + j0 + ((op ^ (f & 7)) << 3),
                  (void*)(s_vT + (p * 256 + wv * 64) * 8));
        }
        {   // packed A-gen: 4 j x 8 k, b64 stores
            float cix = s_ci[ia][0], ciy = s_ci[ia][1], ciz = s_ci[ia][2], l2i = s_ci[ia][3];
            float d2a[4], csa[4];
#pragma unroll
            for (int jj = 0; jj < 4; jj++) {
                float l2j = jx[jj] * jx[jj] + jy[jj] * jy[jj] + jz[jj] * jz[jj];
                float dot = cix * jx[jj] + ciy * jy[jj] + ciz * jz[jj];
                d2a[jj] = fabsf(l2i + l2j - 2.f * dot) + EPSF;
                csa[jj] = dot / sqrtf((l2i + EPSF) * (l2j + EPSF));
            }
            const float* up = &s_u[ia][0];
            const float* wp = &s_w[ia][0];
#pragma unroll
            for (int k = 0; k < 8; k++) {
                float uu = up[k], ww = wp[k], om = 1.f - ww;
                float a0 = __expf(-d2a[0] * uu) * (ww * csa[0] + om);
                float a1 = __expf(-d2a[1] * uu) * (ww * csa[1] + om);
                float a2 = __expf(-d2a[2] * uu) * (ww * csa[2] + om);
                float a3 = __expf(-d2a[3] * uu) * (ww * csa[3] + om);
                int row = ia * 8 + k;
                uint2 pk = make_uint2(pack2(a0, a1), pack2(a2, a3));
                *(uint2*)&s_A[(row << 6) + ((oct ^ (row & 7)) << 3) + half] = pk;
            }
        }
        __syncthreads();               // DMA + A-writes visible
#pragma unroll
        for (int ks = 0; ks < 2; ks++) {
            int o = ks * 4 + quad;
            bf16x8 a0 = *(const bf16x8*)&s_A[swz(wv * 32 + l15, o)];
            bf16x8 a1 = *(const bf16x8*)&s_A[swz(wv * 32 + 16 + l15, o)];
#pragma unroll
            for (int cf = 0; cf < 4; cf++) {
                bf16x8 bv = *(const bf16x8*)&s_vT[swz(cf * 16 + l15, o)];
                acc[0][cf] = MFMA_16x16x32(a0, bv, acc[0][cf]);
                acc[1][cf] = MFMA_16x16x32(a1, bv, acc[1][cf]);
            }
        }
    }

    // ---- phase C: msg acc -> s_X cols 64..575 ----
#pragma unroll
    for (int rf = 0; rf < 2; rf++)
#pragma unroll
        for (int cf = 0; cf < 4; cf++)
#pragma unroll
            for (int r = 0; r < 4; r++) {
                int arow = wv * 32 + rf * 16 + quad * 4 + r;
                int i = arow >> 3, k = arow & 7;
                s_X[i * 584 + 64 + k * 64 + cf * 16 + l15] = f2bf(acc[rf][cf][r]);
            }
    __syncthreads();                   // s_X complete for all waves

    // ---- phase D: barrier-free mini-GEMM, W direct from global ----
    f32x4 acc2[2] = {};
#pragma unroll 3
    for (int kc = 0; kc < 576; kc += 64) {
#pragma unroll
        for (int ks = 0; ks < 2; ks++) {
            int o = ks * 4 + quad;
            bf16x8 av = *(const bf16x8*)&s_X[l15 * 584 + kc + o * 8];
#pragma unroll
            for (int cf = 0; cf < 2; cf++) {
                int col = wv * 32 + cf * 16 + l15;
                bf16x8 bv = *(const bf16x8*)&Wt0[(size_t)col * 576 + kc + o * 8];
                acc2[cf] = MFMA_16x16x32(av, bv, acc2[cf]);
            }
        }
    }

    // ---- phase E: tanh/bn/pool -> H0p + transposed VT1 ----
#pragma unroll
    for (int cf = 0; cf < 2; cf++) {
        int col = wv * 32 + cf * 16 + l15;
        float bs = bias[col], gg = bng[col], bb = bnb[col];
        float h0 = gg * tanhf(acc2[cf][0] + bs) + bb;
        float h1 = gg * tanhf(acc2[cf][1] + bs) + bb;
        float h2 = gg * tanhf(acc2[cf][2] + bs) + bb;
        float h3 = gg * tanhf(acc2[cf][3] + bs) + bb;
        float p0 = 0.5f * (h0 + h1), p1 = 0.5f * (h2 + h3);
        int pl = tile * 8 + quad * 2;
        H0p[((size_t)b * 256 + pl) * 128 + col] = p0;
        H0p[((size_t)b * 256 + pl + 1) * 128 + col] = p1;
        VT1[((size_t)b * 128 + col) * 256 + pl]     = f2bf(p0);
        VT1[((size_t)b * 128 + col) * 256 + pl + 1] = f2bf(p1);
    }
}

// ---------------------------------------------------------------------------
// layer1_fused: 8 pooled-rows/block. Grid 512 = 16 b x 32 tiles. LDS ~43 KB.
// Same phases; phase D barrier-free with global W frags.
// ---------------------------------------------------------------------------
__global__ __launch_bounds__(256)
void layer1_fused(const u16* __restrict__ VT1, const float* __restrict__ C,
                  const float* __restrict__ H0p,
                  const float* __restrict__ gw, const float* __restrict__ gb,
                  const float* __restrict__ aw, const float* __restrict__ ab,
                  const u16* __restrict__ Wt1, const float* __restrict__ bias,
                  const float* __restrict__ bng, const float* __restrict__ bnb,
                  float* __restrict__ H1p) {
    int b = blockIdx.x >> 5, tile = blockIdx.x & 31;
    int i0 = tile * 8;
    int tid = threadIdx.x;
    int wv = tid >> 6, lane = tid & 63, quad = lane >> 4, l15 = lane & 15;

    __shared__ __align__(16) u16 s_mem[12288];   // s_vT 8192 | s_A 4096
    __shared__ __align__(16) u16 s_X1[8 * 1160]; // 18.6 KB
    __shared__ __align__(16) float s_ci[8][4];
    __shared__ float s_u[8][KK];
    __shared__ float s_w[8][KK];

    u16* s_vT = s_mem;
    u16* s_A  = s_mem + 8192;

    // ---- phase A ----
    if (wv < 2) {   // uw over H0p rows (F=128)
        int t = tid & 63;
        int i = t >> 3, k = t & 7;
        const float4* xr = (const float4*)(H0p + ((size_t)b * 256 + i0 + i) * 128);
        const float* wm = (wv == 0) ? gw : aw;
        float s = 0.f;
#pragma unroll
        for (int f4 = 0; f4 < 32; f4++) {
            float4 x = xr[f4];
            s += x.x * wm[(f4 * 4 + 0) * 8 + k] + x.y * wm[(f4 * 4 + 1) * 8 + k]
               + x.z * wm[(f4 * 4 + 2) * 8 + k] + x.w * wm[(f4 * 4 + 3) * 8 + k];
        }
        if (wv == 0) s_u[i][k] = softplusf(s + gb[k]);
        else         s_w[i][k] = sigmoidf_(s + ab[k]);
    }
    if (tid < 8) {  // pooled coords
        const float* cp = C + ((size_t)b * 512 + 2 * (i0 + tid)) * 3;
        float x = 0.5f * (cp[0] + cp[3]);
        float y = 0.5f * (cp[1] + cp[4]);
        float z = 0.5f * (cp[2] + cp[5]);
        s_ci[tid][0] = x; s_ci[tid][1] = y; s_ci[tid][2] = z;
        s_ci[tid][3] = x * x + y * y + z * z;
    }
    {   // H0p rows -> s_X1 cols 0..127 (bf16)
        int row = tid >> 5, f4 = tid & 31;
        float4 x = *(const float4*)(H0p + ((size_t)b * 256 + i0 + row) * 128 + f4 * 4);
        *(uint32*)&s_X1[row * 1160 + f4 * 4]     = pack2(x.x, x.y);
        *(uint32*)&s_X1[row * 1160 + f4 * 4 + 2] = pack2(x.z, x.w);
    }

    // A-gen mapping: kh = tid>>7 (k-half), ia = (tid>>4)&7, jg = tid&15
    int kh = tid >> 7, ia = (tid >> 4) & 7, jg = tid & 15;
    int oct = jg >> 1, half = (jg & 1) << 2;

    // ---- phase B: msg K-loop (4 x 64 j) ----
    f32x4 acc[8] = {};
    for (int j0 = 0; j0 < 256; j0 += 64) {
        // pooled coords for this thread's 4 j (8 raw nodes = 24 floats)
        const float4* cp4 = (const float4*)(C + ((size_t)b * 512 + 2 * (j0 + jg * 4)) * 3);
        float4 q0 = cp4[0], q1 = cp4[1], q2 = cp4[2], q3 = cp4[3], q4 = cp4[4], q5 = cp4[5];
        float r[24] = {q0.x,q0.y,q0.z,q0.w, q1.x,q1.y,q1.z,q1.w, q2.x,q2.y,q2.z,q2.w,
                       q3.x,q3.y,q3.z,q3.w, q4.x,q4.y,q4.z,q4.w, q5.x,q5.y,q5.z,q5.w};
        float jx[4], jy[4], jz[4];
#pragma unroll
        for (int jj = 0; jj < 4; jj++) {
            jx[jj] = 0.5f * (r[6 * jj] + r[6 * jj + 3]);
            jy[jj] = 0.5f * (r[6 * jj + 1] + r[6 * jj + 4]);
            jz[jj] = 0.5f * (r[6 * jj + 2] + r[6 * jj + 5]);
        }
        __syncthreads();
#pragma unroll
        for (int p = 0; p < 4; p++) {  // DMA H^T tile [128 f][64 j]
            int s = p * 256 + wv * 64 + lane;
            int f = s >> 3, op = s & 7;
            g2l16(VT1 + ((size_t)b * 128 + f) * 256 + j0 + ((op ^ (f & 7)) << 3),
                  (void*)(s_vT + (p * 256 + wv * 64) * 8));
        }
        {   // packed A-gen: 4 j x 4 k (this k-half), b64 stores
            float cix = s_ci[ia][0], ciy = s_ci[ia][1], ciz = s_ci[ia][2], l2i = s_ci[ia][3];
            float d2a[4], csa[4];
#pragma unroll
            for (int jj = 0; jj < 4; jj++) {
                float l2j = jx[jj] * jx[jj] + jy[jj] * jy[jj] + jz[jj] * jz[jj];
                float dot = cix * jx[jj] + ciy * jy[jj] + ciz * jz[jj];
                d2a[jj] = fabsf(l2i + l2j - 2.f * dot) + EPSF;
                csa[jj] = dot / sqrtf((l2i + EPSF) * (l2j + EPSF));
            }
            const float* up = &s_u[ia][kh * 4];
            const float* wp = &s_w[ia][kh * 4];
#pragma unroll
            for (int kk = 0; kk < 4; kk++) {
                float uu = up[kk], ww = wp[kk], om = 1.f - ww;
                float a0 = __expf(-d2a[0] * uu) * (ww * csa[0] + om);
                float a1 = __expf(-d2a[1] * uu) * (ww * csa[1] + om);
                float a2 = __expf(-d2a[2] * uu) * (ww * csa[2] + om);
                float a3 = __expf(-d2a[3] * uu) * (ww * csa[3] + om);
                int row = ia * 8 + kh * 4 + kk;
                uint2 pk = make_uint2(pack2(a0, a1), pack2(a2, a3));
                *(uint2*)&s_A[(row << 6) + ((oct ^ (row & 7)) << 3) + half] = pk;
            }
        }
        __syncthreads();
#pragma unroll
        for (int ks = 0; ks < 2; ks++) {
            int o = ks * 4 + quad;
            bf16x8 a0 = *(const bf16x8*)&s_A[swz(wv * 16 + l15, o)];
#pragma unroll
            for (int cf = 0; cf < 8; cf++) {
                bf16x8 bv = *(const bf16x8*)&s_vT[swz(cf * 16 + l15, o)];
                acc[cf] = MFMA_16x16x32(a0, bv, acc[cf]);
            }
        }
    }

    // ---- phase C: msg acc -> s_X1 cols 128..1151 ----
#pragma unroll
    for (int cf = 0; cf < 8; cf++)
#pragma unroll
        for (int r = 0; r < 4; r++) {
            int arow = wv * 16 + quad * 4 + r;
            int i = arow >> 3, k = arow & 7;
            s_X1[i * 1160 + 128 + k * 128 + cf * 16 + l15] = f2bf(acc[cf][r]);
        }
    __syncthreads();

    // ---- phase D: barrier-free mini-GEMM, W direct from global ----
    f32x4 acc2[4] = {};
#pragma unroll 2
    for (int kc = 0; kc < 1152; kc += 64) {
#pragma unroll
        for (int ks = 0; ks < 2; ks++) {
            int o = ks * 4 + quad;
            bf16x8 av = *(const bf16x8*)&s_X1[(l15 & 7) * 1160 + kc + o * 8];
#pragma unroll
            for (int cf = 0; cf < 4; cf++) {
                int col = wv * 64 + cf * 16 + l15;
                bf16x8 bv = *(const bf16x8*)&Wt1[(size_t)col * 1152 + kc + o * 8];
                acc2[cf] = MFMA_16x16x32(av, bv, acc2[cf]);
            }
        }
    }

    // ---- phase E: tanh/bn/pool -> H1p (valid C rows 0..7 -> quads 0,1) ----
#pragma unroll
    for (int cf = 0; cf < 4; cf++) {
        int col = wv * 64 + cf * 16 + l15;
        float bs = bias[col], gg = bng[col], bb = bnb[col];
        float h0 = gg * tanhf(acc2[cf][0] + bs) + bb;
        float h1 = gg * tanhf(acc2[cf][1] + bs) + bb;
        float h2 = gg * tanhf(acc2[cf][2] + bs) + bb;
        float h3 = gg * tanhf(acc2[cf][3] + bs) + bb;
        if (quad < 2) {
            float p0 = 0.5f * (h0 + h1), p1 = 0.5f * (h2 + h3);
            int pl = tile * 4 + quad * 2;
            H1p[((size_t)b * 128 + pl) * 256 + col] = p0;
            H1p[((size_t)b * 128 + pl + 1) * 256 + col] = p1;
        }
    }
}

// ---------------------------------------------------------------------------
// FC split-K: grid 512 = 4 col-splits x 128 k-splits (m-chunks of 256).
// ---------------------------------------------------------------------------
__global__ __launch_bounds__(256)
void fc_partial_kernel(const float* __restrict__ Flat, const float* __restrict__ W,
                       float* __restrict__ P) {
    int cs = blockIdx.x & 3, ks = blockIdx.x >> 2;
    int m0 = ks * 256;
    int c4 = threadIdx.x & 31;
    int msub = threadIdx.x >> 5;

    __shared__ __align__(16) float xT[256][16];

#pragma unroll
    for (int q = 0; q < 16; q++) {
        int idx = q * 256 + threadIdx.x;
        int b = idx >> 8, mm = idx & 255;
        int bg = (b >> 2) ^ (mm & 3);
        xT[mm][(bg << 2) + (b & 3)] = Flat[(size_t)b * 32768 + m0 + mm];
    }
    __syncthreads();

    const float4* W4 = (const float4*)W;
    float4 acc[16] = {};

    for (int h = 0; h < 4; h++) {
        float4 wbuf[8];
#pragma unroll
        for (int i = 0; i < 8; i++) {
            int mm = msub * 32 + h * 8 + i;
            wbuf[i] = W4[(size_t)(m0 + mm) * 128 + cs * 32 + c4];
        }
#pragma unroll
        for (int i = 0; i < 8; i++) {
            int mm = msub * 32 + h * 8 + i;
#pragma unroll
            for (int bg = 0; bg < 4; bg++) {
                float4 xv = *(const float4*)&xT[mm][((bg ^ (mm & 3)) << 2)];
                acc[bg * 4 + 0].x += xv.x * wbuf[i].x; acc[bg * 4 + 0].y += xv.x * wbuf[i].y;
                acc[bg * 4 + 0].z += xv.x * wbuf[i].z; acc[bg * 4 + 0].w += xv.x * wbuf[i].w;
                acc[bg * 4 + 1].x += xv.y * wbuf[i].x; acc[bg * 4 + 1].y += xv.y * wbuf[i].y;
                acc[bg * 4 + 1].z += xv.y * wbuf[i].z; acc[bg * 4 + 1].w += xv.y * wbuf[i].w;
                acc[bg * 4 + 2].x += xv.z * wbuf[i].x; acc[bg * 4 + 2].y += xv.z * wbuf[i].y;
                acc[bg * 4 + 2].z += xv.z * wbuf[i].z; acc[bg * 4 + 2].w += xv.z * wbuf[i].w;
                acc[bg * 4 + 3].x += xv.w * wbuf[i].x; acc[bg * 4 + 3].y += xv.w * wbuf[i].y;
                acc[bg * 4 + 3].z += xv.w * wbuf[i].z; acc[bg * 4 + 3].w += xv.w * wbuf[i].w;
            }
        }
    }
    __syncthreads();
    __shared__ __align__(16) float red[8][32][4];
#pragma unroll
    for (int b = 0; b < 16; b++) {
        red[msub][c4][0] = acc[b].x; red[msub][c4][1] = acc[b].y;
        red[msub][c4][2] = acc[b].z; red[msub][c4][3] = acc[b].w;
        __syncthreads();
        if (msub == 0) {
            float4 s = make_float4(0.f, 0.f, 0.f, 0.f);
#pragma unroll
            for (int m = 0; m < 8; m++) {
                s.x += red[m][c4][0]; s.y += red[m][c4][1];
                s.z += red[m][c4][2]; s.w += red[m][c4][3];
            }
            *(float4*)&P[((size_t)ks * 16 + b) * 512 + cs * 128 + c4 * 4] = s;
        }
        __syncthreads();
    }
}

// grid 256: block = 32 outputs; thread (o, kg) sums 16 ks; LDS reduce 8->1
__global__ __launch_bounds__(256)
void fc_reduce_kernel(const float* __restrict__ P, const float* __restrict__ fcb,
                      float* __restrict__ out) {
    __shared__ float red[8][33];
    int o = blockIdx.x * 32 + (threadIdx.x & 31);
    int kg = threadIdx.x >> 5;
    float s = 0.f;
#pragma unroll
    for (int q = 0; q < 16; q++) s += P[(size_t)(kg * 16 + q) * 8192 + o];
    red[kg][threadIdx.x & 31] = s;
    __syncthreads();
    if (kg == 0) {
        float t = fcb[o & 511];
#pragma unroll
        for (int m = 0; m < 8; m++) t += red[m][threadIdx.x & 31];
        out[o] = 1.f / (1.f + expf(-t));
    }
}

// ---------------------------------------------------------------------------
extern "C" void kernel_launch(void* const* d_in, const int* in_sizes, int n_in,
                              void* d_out, int out_size, void* d_ws, size_t ws_size,
                              hipStream_t stream) {
    const float* V     = (const float*)d_in[0];
    const float* C     = (const float*)d_in[1];
    const float* gk_w0 = (const float*)d_in[2];
    const float* gk_b0 = (const float*)d_in[3];
    const float* ac_w0 = (const float*)d_in[4];
    const float* ac_b0 = (const float*)d_in[5];
    const float* gc_w0 = (const float*)d_in[6];
    const float* gc_b0 = (const float*)d_in[7];
    const float* bn_g0 = (const float*)d_in[8];
    const float* bn_b0 = (const float*)d_in[9];
    const float* gk_w1 = (const float*)d_in[10];
    const float* gk_b1 = (const float*)d_in[11];
    const float* ac_w1 = (const float*)d_in[12];
    const float* ac_b1 = (const float*)d_in[13];
    const float* gc_w1 = (const float*)d_in[14];
    const float* gc_b1 = (const float*)d_in[15];
    const float* bn_g1 = (const float*)d_in[16];
    const float* bn_b1 = (const float*)d_in[17];
    const float* fc_w  = (const float*)d_in[18];
    const float* fc_b  = (const float*)d_in[19];
    float* out = (float*)d_out;

    float* H0p = (float*)d_ws;        // [4096][128] = 524288 f32
    float* H1p = H0p + 524288;        // [2048][256] = 524288 f32
    float* P   = H1p + 524288;        // 128*16*512 = 1048576 f32
    u16* VT0 = (u16*)(P + 1048576);   // [16][64][512]  = 524288 u16
    u16* VT1 = VT0 + 524288;          // [16][128][256] = 524288 u16
    u16* Wt0 = VT1 + 524288;          // [128][576]  = 73728 u16
    u16* Wt1 = Wt0 + 73728;           // [256][1152] = 294912 u16

    prep_kernel<<<218, 256, 0, stream>>>(V, gc_w0, gc_w1, VT0, Wt0, Wt1);
    layer0_fused<<<512, 256, 0, stream>>>(VT0, C, V, gk_w0, gk_b0, ac_w0, ac_b0,
                                          Wt0, gc_b0, bn_g0, bn_b0, H0p, VT1);
    layer1_fused<<<512, 256, 0, stream>>>(VT1, C, H0p, gk_w1, gk_b1, ac_w1, ac_b1,
                                          Wt1, gc_b1, bn_g1, bn_b1, H1p);
    fc_partial_kernel<<<512, 256, 0, stream>>>(H1p, fc_w, P);
    fc_reduce_kernel<<<256, 256, 0, stream>>>(P, fc_b, out);
}

// Round 8
// 206.378 us; speedup vs baseline: 1.0650x; 1.0650x over previous
//
#include <hip/hip_runtime.h>
#include <math.h>

#define KK 8
#define EPSF 1e-9f

typedef unsigned int   uint32;
typedef unsigned short u16;
typedef __attribute__((ext_vector_type(8))) short bf16x8;
typedef __attribute__((ext_vector_type(4))) float f32x4;

#define MFMA_16x16x32(a, b, c) __builtin_amdgcn_mfma_f32_16x16x32_bf16(a, b, c, 0, 0, 0)

typedef __attribute__((address_space(1))) const unsigned int glob_cu32;
typedef __attribute__((address_space(3))) unsigned int lds_u32;
// async global->LDS DMA, 16B per lane; LDS dest = wave-uniform base + lane*16
__device__ __forceinline__ void g2l16(const void* gsrc, void* ldst) {
    __builtin_amdgcn_global_load_lds((glob_cu32*)gsrc, (lds_u32*)ldst, 16, 0, 0);
}

// swizzled ushort index of logical octet o (8 bf16) in a [row][64] LDS tile
__device__ __forceinline__ int swz(int row, int o) {
    return (row << 6) + (((o) ^ (row & 7)) << 3);
}

__device__ __forceinline__ float softplusf(float x) {
    return x > 0.0f ? x + log1pf(expf(-x)) : log1pf(expf(x));
}
__device__ __forceinline__ float sigmoidf_(float x) {
    return 1.0f / (1.0f + expf(-x));
}
// fp32 -> bf16 round-to-nearest-even
__device__ __forceinline__ u16 f2bf(float f) {
    union { float f; uint32 u; } v; v.f = f;
    uint32 u = v.u;
    return (u16)((u + 0x7FFFu + ((u >> 16) & 1u)) >> 16);
}
__device__ __forceinline__ uint32 pack2(float a, float b) {
    return (uint32)f2bf(a) | ((uint32)f2bf(b) << 16);
}

// ---------------------------------------------------------------------------
// prep: V->VT0 bf16 [16][64][512] (transposed), gc_w0->Wt0 bf16 [128][576],
//       gc_w1->Wt1 bf16 [256][1152].
// ---------------------------------------------------------------------------
__global__ __launch_bounds__(256)
void prep_kernel(const float* __restrict__ V, const float* __restrict__ W0,
                 const float* __restrict__ W1, u16* __restrict__ VT0,
                 u16* __restrict__ Wt0, u16* __restrict__ Wt1) {
    __shared__ float s[64][65];
    int blk = blockIdx.x, tid = threadIdx.x;
    if (blk < 128) {            // V [16][512][64] -> VT0 [16][64][512]
        int b = blk >> 3, rt = blk & 7;
#pragma unroll
        for (int t = 0; t < 16; t++) {
            int idx = t * 256 + tid; int r = idx >> 6, c = idx & 63;
            s[r][c] = V[((size_t)b * 512 + rt * 64 + r) * 64 + c];
        }
        __syncthreads();
#pragma unroll
        for (int t = 0; t < 16; t++) {
            int idx = t * 256 + tid; int f = idx >> 6, j = idx & 63;
            VT0[((size_t)b * 64 + f) * 512 + rt * 64 + j] = f2bf(s[j][f]);
        }
    } else if (blk < 146) {     // W0 [576][128] -> Wt0 [128][576]
        int t0 = blk - 128; int rt = t0 >> 1, ct = t0 & 1;
#pragma unroll
        for (int t = 0; t < 16; t++) {
            int idx = t * 256 + tid; int r = idx >> 6, c = idx & 63;
            s[r][c] = W0[((size_t)rt * 64 + r) * 128 + ct * 64 + c];
        }
        __syncthreads();
#pragma unroll
        for (int t = 0; t < 16; t++) {
            int idx = t * 256 + tid; int f = idx >> 6, j = idx & 63;
            Wt0[((size_t)ct * 64 + f) * 576 + rt * 64 + j] = f2bf(s[j][f]);
        }
    } else {                    // W1 [1152][256] -> Wt1 [256][1152]
        int t0 = blk - 146; int rt = t0 >> 2, ct = t0 & 3;
#pragma unroll
        for (int t = 0; t < 16; t++) {
            int idx = t * 256 + tid; int r = idx >> 6, c = idx & 63;
            s[r][c] = W1[((size_t)rt * 64 + r) * 256 + ct * 64 + c];
        }
        __syncthreads();
#pragma unroll
        for (int t = 0; t < 16; t++) {
            int idx = t * 256 + tid; int f = idx >> 6, j = idx & 63;
            Wt1[((size_t)ct * 64 + f) * 1152 + rt * 64 + j] = f2bf(s[j][f]);
        }
    }
}

// ---------------------------------------------------------------------------
// layer0_fused: 16 node-rows/block. Grid 512 = 16 b x 32 tiles. LDS ~52 KB.
//   A: uw row-proj, ci, V->s_X[:, :64]
//   B: j-loop (8x64): packed A-gen -> s_A, DMA V^T, msg MFMA
//   C: acc -> s_X[:, 64:576]
//   D: double-buffered DMA-staged mini-GEMM (DMA(c+1) overlaps MFMA(c))
//   E: tanh/bn/pool -> H0p fp32 + VT1 bf16 (transposed)
// ---------------------------------------------------------------------------
__global__ __launch_bounds__(256)
void layer0_fused(const u16* __restrict__ VT0, const float* __restrict__ C,
                  const float* __restrict__ V,
                  const float* __restrict__ gw, const float* __restrict__ gb,
                  const float* __restrict__ aw, const float* __restrict__ ab,
                  const u16* __restrict__ Wt0, const float* __restrict__ bias,
                  const float* __restrict__ bng, const float* __restrict__ bnb,
                  float* __restrict__ H0p, u16* __restrict__ VT1) {
    int b = blockIdx.x >> 5, tile = blockIdx.x & 31;
    int i0 = tile * 16;
    int tid = threadIdx.x;
    int wv = tid >> 6, lane = tid & 63, quad = lane >> 4, l15 = lane & 15;

    __shared__ __align__(16) u16 s_mem[16384];   // B: s_vT 4096 | s_A 8192 ; D: 2x 8192 dbuf
    __shared__ __align__(16) u16 s_X[16 * 584];  // 18.7 KB, stride 584
    __shared__ __align__(16) float s_ci[16][4];
    __shared__ float s_u[16][KK];
    __shared__ float s_w[16][KK];

    u16* s_vT = s_mem;
    u16* s_A  = s_mem + 4096;

    // ---- phase A ----
    {
        int t = tid & 127;
        int i = t >> 3, k = t & 7;
        const float4* xr = (const float4*)(V + ((size_t)b * 512 + i0 + i) * 64);
        const float* wm = (tid < 128) ? gw : aw;
        float s = 0.f;
#pragma unroll
        for (int f4 = 0; f4 < 16; f4++) {
            float4 x = xr[f4];
            s += x.x * wm[(f4 * 4 + 0) * 8 + k] + x.y * wm[(f4 * 4 + 1) * 8 + k]
               + x.z * wm[(f4 * 4 + 2) * 8 + k] + x.w * wm[(f4 * 4 + 3) * 8 + k];
        }
        if (tid < 128) s_u[i][k] = softplusf(s + gb[k]);
        else           s_w[i][k] = sigmoidf_(s + ab[k]);
    }
    if (tid < 16) {
        const float* cp = C + ((size_t)b * 512 + i0 + tid) * 3;
        float x = cp[0], y = cp[1], z = cp[2];
        s_ci[tid][0] = x; s_ci[tid][1] = y; s_ci[tid][2] = z;
        s_ci[tid][3] = x * x + y * y + z * z;
    }
    {   // V rows -> s_X cols 0..63 (bf16)
        int row = tid >> 4, f4 = tid & 15;
        float4 x = *(const float4*)(V + ((size_t)b * 512 + i0 + row) * 64 + f4 * 4);
        *(uint32*)&s_X[row * 584 + f4 * 4]     = pack2(x.x, x.y);
        *(uint32*)&s_X[row * 584 + f4 * 4 + 2] = pack2(x.z, x.w);
    }

    // A-gen thread mapping: i = tid>>4 (16), jg = tid&15 (4-j group)
    int ia = tid >> 4, jg = tid & 15;
    int oct = jg >> 1, half = (jg & 1) << 2;

    // ---- phase B: msg K-loop ----
    f32x4 acc[2][4] = {};
    for (int j0 = 0; j0 < 512; j0 += 64) {
        const float4* cp4 = (const float4*)(C + ((size_t)b * 512 + j0 + jg * 4) * 3);
        float4 q0 = cp4[0], q1 = cp4[1], q2 = cp4[2];
        float jx[4] = {q0.x, q0.w, q1.z, q2.y};
        float jy[4] = {q0.y, q1.x, q1.w, q2.z};
        float jz[4] = {q0.z, q1.y, q2.x, q2.w};
        __syncthreads();               // prev-iter LDS reads drained
#pragma unroll
        for (int p = 0; p < 2; p++) {  // DMA V^T tile [64 f][64 j]
            int s = p * 256 + wv * 64 + lane;
            int f = s >> 3, op = s & 7;
            g2l16(VT0 + ((size_t)b * 64 + f) * 512 + j0 + ((op ^ (f & 7)) << 3),
                  (void*)(s_vT + (p * 256 + wv * 64) * 8));
        }
        {   // packed A-gen: 4 j x 8 k, b64 stores
            float cix = s_ci[ia][0], ciy = s_ci[ia][1], ciz = s_ci[ia][2], l2i = s_ci[ia][3];
            float d2a[4], csa[4];
#pragma unroll
            for (int jj = 0; jj < 4; jj++) {
                float l2j = jx[jj] * jx[jj] + jy[jj] * jy[jj] + jz[jj] * jz[jj];
                float dot = cix * jx[jj] + ciy * jy[jj] + ciz * jz[jj];
                d2a[jj] = fabsf(l2i + l2j - 2.f * dot) + EPSF;
                csa[jj] = dot / sqrtf((l2i + EPSF) * (l2j + EPSF));
            }
            const float* up = &s_u[ia][0];
            const float* wp = &s_w[ia][0];
#pragma unroll
            for (int k = 0; k < 8; k++) {
                float uu = up[k], ww = wp[k], om = 1.f - ww;
                float a0 = __expf(-d2a[0] * uu) * (ww * csa[0] + om);
                float a1 = __expf(-d2a[1] * uu) * (ww * csa[1] + om);
                float a2 = __expf(-d2a[2] * uu) * (ww * csa[2] + om);
                float a3 = __expf(-d2a[3] * uu) * (ww * csa[3] + om);
                int row = ia * 8 + k;
                uint2 pk = make_uint2(pack2(a0, a1), pack2(a2, a3));
                *(uint2*)&s_A[(row << 6) + ((oct ^ (row & 7)) << 3) + half] = pk;
            }
        }
        __syncthreads();               // DMA + A-writes visible
#pragma unroll
        for (int ks = 0; ks < 2; ks++) {
            int o = ks * 4 + quad;
            bf16x8 a0 = *(const bf16x8*)&s_A[swz(wv * 32 + l15, o)];
            bf16x8 a1 = *(const bf16x8*)&s_A[swz(wv * 32 + 16 + l15, o)];
#pragma unroll
            for (int cf = 0; cf < 4; cf++) {
                bf16x8 bv = *(const bf16x8*)&s_vT[swz(cf * 16 + l15, o)];
                acc[0][cf] = MFMA_16x16x32(a0, bv, acc[0][cf]);
                acc[1][cf] = MFMA_16x16x32(a1, bv, acc[1][cf]);
            }
        }
    }

    // ---- phase C: msg acc -> s_X cols 64..575 ----
#pragma unroll
    for (int rf = 0; rf < 2; rf++)
#pragma unroll
        for (int cf = 0; cf < 4; cf++)
#pragma unroll
            for (int r = 0; r < 4; r++) {
                int arow = wv * 32 + rf * 16 + quad * 4 + r;
                int i = arow >> 3, k = arow & 7;
                s_X[i * 584 + 64 + k * 64 + cf * 16 + l15] = f2bf(acc[rf][cf][r]);
            }
    __syncthreads();                   // s_X ready; s_mem free

    // ---- phase D: double-buffered mini-GEMM [16 x 576] @ Wt0^T ----
    // chunk = [128 c][64 k] = 16 KB, staged swizzled; DMA(c+1) overlaps MFMA(c)
    {
#pragma unroll
        for (int p = 0; p < 4; p++) {  // prologue: chunk 0 -> buf 0
            int s = p * 256 + wv * 64 + lane;
            int cc = s >> 3, op = s & 7;
            g2l16(Wt0 + (size_t)cc * 576 + ((op ^ (cc & 7)) << 3),
                  (void*)(s_mem + (p * 256 + wv * 64) * 8));
        }
    }
    f32x4 acc2[2] = {};
    for (int c = 0; c < 9; c++) {
        u16* cur = s_mem + (c & 1) * 8192;
        u16* nxt = s_mem + ((c + 1) & 1) * 8192;
        __syncthreads();               // drains DMA(c); protects nxt reuse
        if (c < 8) {
            int kcn = (c + 1) * 64;
#pragma unroll
            for (int p = 0; p < 4; p++) {
                int s = p * 256 + wv * 64 + lane;
                int cc = s >> 3, op = s & 7;
                g2l16(Wt0 + (size_t)cc * 576 + kcn + ((op ^ (cc & 7)) << 3),
                      (void*)(nxt + (p * 256 + wv * 64) * 8));
            }
        }
        int kc = c * 64;
#pragma unroll
        for (int ks = 0; ks < 2; ks++) {
            int o = ks * 4 + quad;
            bf16x8 av = *(const bf16x8*)&s_X[l15 * 584 + kc + o * 8];
#pragma unroll
            for (int cf = 0; cf < 2; cf++) {
                bf16x8 bv = *(const bf16x8*)&cur[swz(wv * 32 + cf * 16 + l15, o)];
                acc2[cf] = MFMA_16x16x32(av, bv, acc2[cf]);
            }
        }
    }

    // ---- phase E: tanh/bn/pool -> H0p + transposed VT1 ----
#pragma unroll
    for (int cf = 0; cf < 2; cf++) {
        int col = wv * 32 + cf * 16 + l15;
        float bs = bias[col], gg = bng[col], bb = bnb[col];
        float h0 = gg * tanhf(acc2[cf][0] + bs) + bb;
        float h1 = gg * tanhf(acc2[cf][1] + bs) + bb;
        float h2 = gg * tanhf(acc2[cf][2] + bs) + bb;
        float h3 = gg * tanhf(acc2[cf][3] + bs) + bb;
        float p0 = 0.5f * (h0 + h1), p1 = 0.5f * (h2 + h3);
        int pl = tile * 8 + quad * 2;
        H0p[((size_t)b * 256 + pl) * 128 + col] = p0;
        H0p[((size_t)b * 256 + pl + 1) * 128 + col] = p1;
        VT1[((size_t)b * 128 + col) * 256 + pl]     = f2bf(p0);
        VT1[((size_t)b * 128 + col) * 256 + pl + 1] = f2bf(p1);
    }
}

// ---------------------------------------------------------------------------
// layer1_fused: 8 pooled-rows/block. Grid 512 = 16 b x 32 tiles. LDS ~52 KB.
// Phase D: two 128-col passes x 18 chunks of [128 c][64 k], double-buffered.
// ---------------------------------------------------------------------------
__global__ __launch_bounds__(256)
void layer1_fused(const u16* __restrict__ VT1, const float* __restrict__ C,
                  const float* __restrict__ H0p,
                  const float* __restrict__ gw, const float* __restrict__ gb,
                  const float* __restrict__ aw, const float* __restrict__ ab,
                  const u16* __restrict__ Wt1, const float* __restrict__ bias,
                  const float* __restrict__ bng, const float* __restrict__ bnb,
                  float* __restrict__ H1p) {
    int b = blockIdx.x >> 5, tile = blockIdx.x & 31;
    int i0 = tile * 8;
    int tid = threadIdx.x;
    int wv = tid >> 6, lane = tid & 63, quad = lane >> 4, l15 = lane & 15;

    __shared__ __align__(16) u16 s_mem[16384];   // B: s_vT 8192 | s_A 4096 ; D: 2x 8192 dbuf
    __shared__ __align__(16) u16 s_X1[8 * 1160]; // 18.6 KB
    __shared__ __align__(16) float s_ci[8][4];
    __shared__ float s_u[8][KK];
    __shared__ float s_w[8][KK];

    u16* s_vT = s_mem;
    u16* s_A  = s_mem + 8192;

    // ---- phase A ----
    if (wv < 2) {   // uw over H0p rows (F=128)
        int t = tid & 63;
        int i = t >> 3, k = t & 7;
        const float4* xr = (const float4*)(H0p + ((size_t)b * 256 + i0 + i) * 128);
        const float* wm = (wv == 0) ? gw : aw;
        float s = 0.f;
#pragma unroll
        for (int f4 = 0; f4 < 32; f4++) {
            float4 x = xr[f4];
            s += x.x * wm[(f4 * 4 + 0) * 8 + k] + x.y * wm[(f4 * 4 + 1) * 8 + k]
               + x.z * wm[(f4 * 4 + 2) * 8 + k] + x.w * wm[(f4 * 4 + 3) * 8 + k];
        }
        if (wv == 0) s_u[i][k] = softplusf(s + gb[k]);
        else         s_w[i][k] = sigmoidf_(s + ab[k]);
    }
    if (tid < 8) {  // pooled coords
        const float* cp = C + ((size_t)b * 512 + 2 * (i0 + tid)) * 3;
        float x = 0.5f * (cp[0] + cp[3]);
        float y = 0.5f * (cp[1] + cp[4]);
        float z = 0.5f * (cp[2] + cp[5]);
        s_ci[tid][0] = x; s_ci[tid][1] = y; s_ci[tid][2] = z;
        s_ci[tid][3] = x * x + y * y + z * z;
    }
    {   // H0p rows -> s_X1 cols 0..127 (bf16)
        int row = tid >> 5, f4 = tid & 31;
        float4 x = *(const float4*)(H0p + ((size_t)b * 256 + i0 + row) * 128 + f4 * 4);
        *(uint32*)&s_X1[row * 1160 + f4 * 4]     = pack2(x.x, x.y);
        *(uint32*)&s_X1[row * 1160 + f4 * 4 + 2] = pack2(x.z, x.w);
    }

    // A-gen mapping: kh = tid>>7 (k-half), ia = (tid>>4)&7, jg = tid&15
    int kh = tid >> 7, ia = (tid >> 4) & 7, jg = tid & 15;
    int oct = jg >> 1, half = (jg & 1) << 2;

    // ---- phase B: msg K-loop (4 x 64 j) ----
    f32x4 acc[8] = {};
    for (int j0 = 0; j0 < 256; j0 += 64) {
        const float4* cp4 = (const float4*)(C + ((size_t)b * 512 + 2 * (j0 + jg * 4)) * 3);
        float4 q0 = cp4[0], q1 = cp4[1], q2 = cp4[2], q3 = cp4[3], q4 = cp4[4], q5 = cp4[5];
        float r[24] = {q0.x,q0.y,q0.z,q0.w, q1.x,q1.y,q1.z,q1.w, q2.x,q2.y,q2.z,q2.w,
                       q3.x,q3.y,q3.z,q3.w, q4.x,q4.y,q4.z,q4.w, q5.x,q5.y,q5.z,q5.w};
        float jx[4], jy[4], jz[4];
#pragma unroll
        for (int jj = 0; jj < 4; jj++) {
            jx[jj] = 0.5f * (r[6 * jj] + r[6 * jj + 3]);
            jy[jj] = 0.5f * (r[6 * jj + 1] + r[6 * jj + 4]);
            jz[jj] = 0.5f * (r[6 * jj + 2] + r[6 * jj + 5]);
        }
        __syncthreads();
#pragma unroll
        for (int p = 0; p < 4; p++) {  // DMA H^T tile [128 f][64 j]
            int s = p * 256 + wv * 64 + lane;
            int f = s >> 3, op = s & 7;
            g2l16(VT1 + ((size_t)b * 128 + f) * 256 + j0 + ((op ^ (f & 7)) << 3),
                  (void*)(s_vT + (p * 256 + wv * 64) * 8));
        }
        {   // packed A-gen: 4 j x 4 k (this k-half), b64 stores
            float cix = s_ci[ia][0], ciy = s_ci[ia][1], ciz = s_ci[ia][2], l2i = s_ci[ia][3];
            float d2a[4], csa[4];
#pragma unroll
            for (int jj = 0; jj < 4; jj++) {
                float l2j = jx[jj] * jx[jj] + jy[jj] * jy[jj] + jz[jj] * jz[jj];
                float dot = cix * jx[jj] + ciy * jy[jj] + ciz * jz[jj];
                d2a[jj] = fabsf(l2i + l2j - 2.f * dot) + EPSF;
                csa[jj] = dot / sqrtf((l2i + EPSF) * (l2j + EPSF));
            }
            const float* up = &s_u[ia][kh * 4];
            const float* wp = &s_w[ia][kh * 4];
#pragma unroll
            for (int kk = 0; kk < 4; kk++) {
                float uu = up[kk], ww = wp[kk], om = 1.f - ww;
                float a0 = __expf(-d2a[0] * uu) * (ww * csa[0] + om);
                float a1 = __expf(-d2a[1] * uu) * (ww * csa[1] + om);
                float a2 = __expf(-d2a[2] * uu) * (ww * csa[2] + om);
                float a3 = __expf(-d2a[3] * uu) * (ww * csa[3] + om);
                int row = ia * 8 + kh * 4 + kk;
                uint2 pk = make_uint2(pack2(a0, a1), pack2(a2, a3));
                *(uint2*)&s_A[(row << 6) + ((oct ^ (row & 7)) << 3) + half] = pk;
            }
        }
        __syncthreads();
#pragma unroll
        for (int ks = 0; ks < 2; ks++) {
            int o = ks * 4 + quad;
            bf16x8 a0 = *(const bf16x8*)&s_A[swz(wv * 16 + l15, o)];
#pragma unroll
            for (int cf = 0; cf < 8; cf++) {
                bf16x8 bv = *(const bf16x8*)&s_vT[swz(cf * 16 + l15, o)];
                acc[cf] = MFMA_16x16x32(a0, bv, acc[cf]);
            }
        }
    }

    // ---- phase C: msg acc -> s_X1 cols 128..1151 ----
#pragma unroll
    for (int cf = 0; cf < 8; cf++)
#pragma unroll
        for (int r = 0; r < 4; r++) {
            int arow = wv * 16 + quad * 4 + r;
            int i = arow >> 3, k = arow & 7;
            s_X1[i * 1160 + 128 + k * 128 + cf * 16 + l15] = f2bf(acc[cf][r]);
        }
    __syncthreads();                   // s_X1 ready; s_mem free

    // ---- phase D: dbuf mini-GEMM, 2 col-passes x 18 chunks [128 c][64 k] ----
    {
#pragma unroll
        for (int p = 0; p < 4; p++) {  // prologue: (ch=0, c=0) -> buf 0
            int s = p * 256 + wv * 64 + lane;
            int cc = s >> 3, op = s & 7;
            g2l16(Wt1 + (size_t)cc * 1152 + ((op ^ (cc & 7)) << 3),
                  (void*)(s_mem + (p * 256 + wv * 64) * 8));
        }
    }
    f32x4 acc2[4] = {};
    int g = 0;
    for (int ch = 0; ch < 2; ch++) {
        for (int c = 0; c < 18; c++, g++) {
            u16* cur = s_mem + (g & 1) * 8192;
            u16* nxt = s_mem + ((g + 1) & 1) * 8192;
            __syncthreads();           // drains DMA(g); protects nxt reuse
            if (g < 35) {
                int gn = g + 1;
                int chn = (gn >= 18) ? 1 : 0;
                int colb = chn * 128;
                int kcn = (gn - chn * 18) * 64;
#pragma unroll
                for (int p = 0; p < 4; p++) {
                    int s = p * 256 + wv * 64 + lane;
                    int cc = s >> 3, op = s & 7;
                    g2l16(Wt1 + (size_t)(colb + cc) * 1152 + kcn + ((op ^ (cc & 7)) << 3),
                          (void*)(nxt + (p * 256 + wv * 64) * 8));
                }
            }
            int kc = c * 64;
#pragma unroll
            for (int ks = 0; ks < 2; ks++) {
                int o = ks * 4 + quad;
                bf16x8 av = *(const bf16x8*)&s_X1[(l15 & 7) * 1160 + kc + o * 8];
#pragma unroll
                for (int cf = 0; cf < 2; cf++) {
                    bf16x8 bv = *(const bf16x8*)&cur[swz(wv * 32 + cf * 16 + l15, o)];
                    acc2[ch * 2 + cf] = MFMA_16x16x32(av, bv, acc2[ch * 2 + cf]);
                }
            }
        }
    }

    // ---- phase E: tanh/bn/pool -> H1p (valid C rows 0..7 -> quads 0,1) ----
#pragma unroll
    for (int q = 0; q < 4; q++) {
        int ch = q >> 1, cf = q & 1;
        int col = ch * 128 + wv * 32 + cf * 16 + l15;
        float bs = bias[col], gg = bng[col], bb = bnb[col];
        float h0 = gg * tanhf(acc2[q][0] + bs) + bb;
        float h1 = gg * tanhf(acc2[q][1] + bs) + bb;
        float h2 = gg * tanhf(acc2[q][2] + bs) + bb;
        float h3 = gg * tanhf(acc2[q][3] + bs) + bb;
        if (quad < 2) {
            float p0 = 0.5f * (h0 + h1), p1 = 0.5f * (h2 + h3);
            int pl = tile * 4 + quad * 2;
            H1p[((size_t)b * 128 + pl) * 256 + col] = p0;
            H1p[((size_t)b * 128 + pl + 1) * 256 + col] = p1;
        }
    }
}

// ---------------------------------------------------------------------------
// FC split-K: grid 512 = 4 col-splits x 128 k-splits (m-chunks of 256).
// ---------------------------------------------------------------------------
__global__ __launch_bounds__(256)
void fc_partial_kernel(const float* __restrict__ Flat, const float* __restrict__ W,
                       float* __restrict__ P) {
    int cs = blockIdx.x & 3, ks = blockIdx.x >> 2;
    int m0 = ks * 256;
    int c4 = threadIdx.x & 31;
    int msub = threadIdx.x >> 5;

    __shared__ __align__(16) float xT[256][16];

#pragma unroll
    for (int q = 0; q < 16; q++) {
        int idx = q * 256 + threadIdx.x;
        int b = idx >> 8, mm = idx & 255;
        int bg = (b >> 2) ^ (mm & 3);
        xT[mm][(bg << 2) + (b & 3)] = Flat[(size_t)b * 32768 + m0 + mm];
    }
    __syncthreads();

    const float4* W4 = (const float4*)W;
    float4 acc[16] = {};

    for (int h = 0; h < 4; h++) {
        float4 wbuf[8];
#pragma unroll
        for (int i = 0; i < 8; i++) {
            int mm = msub * 32 + h * 8 + i;
            wbuf[i] = W4[(size_t)(m0 + mm) * 128 + cs * 32 + c4];
        }
#pragma unroll
        for (int i = 0; i < 8; i++) {
            int mm = msub * 32 + h * 8 + i;
#pragma unroll
            for (int bg = 0; bg < 4; bg++) {
                float4 xv = *(const float4*)&xT[mm][((bg ^ (mm & 3)) << 2)];
                acc[bg * 4 + 0].x += xv.x * wbuf[i].x; acc[bg * 4 + 0].y += xv.x * wbuf[i].y;
                acc[bg * 4 + 0].z += xv.x * wbuf[i].z; acc[bg * 4 + 0].w += xv.x * wbuf[i].w;
                acc[bg * 4 + 1].x += xv.y * wbuf[i].x; acc[bg * 4 + 1].y += xv.y * wbuf[i].y;
                acc[bg * 4 + 1].z += xv.y * wbuf[i].z; acc[bg * 4 + 1].w += xv.y * wbuf[i].w;
                acc[bg * 4 + 2].x += xv.z * wbuf[i].x; acc[bg * 4 + 2].y += xv.z * wbuf[i].y;
                acc[bg * 4 + 2].z += xv.z * wbuf[i].z; acc[bg * 4 + 2].w += xv.z * wbuf[i].w;
                acc[bg * 4 + 3].x += xv.w * wbuf[i].x; acc[bg * 4 + 3].y += xv.w * wbuf[i].y;
                acc[bg * 4 + 3].z += xv.w * wbuf[i].z; acc[bg * 4 + 3].w += xv.w * wbuf[i].w;
            }
        }
    }
    __syncthreads();
    __shared__ __align__(16) float red[8][32][4];
#pragma unroll
    for (int b = 0; b < 16; b++) {
        red[msub][c4][0] = acc[b].x; red[msub][c4][1] = acc[b].y;
        red[msub][c4][2] = acc[b].z; red[msub][c4][3] = acc[b].w;
        __syncthreads();
        if (msub == 0) {
            float4 s = make_float4(0.f, 0.f, 0.f, 0.f);
#pragma unroll
            for (int m = 0; m < 8; m++) {
                s.x += red[m][c4][0]; s.y += red[m][c4][1];
                s.z += red[m][c4][2]; s.w += red[m][c4][3];
            }
            *(float4*)&P[((size_t)ks * 16 + b) * 512 + cs * 128 + c4 * 4] = s;
        }
        __syncthreads();
    }
}

// grid 256: block = 32 outputs; thread (o, kg) sums 16 ks; LDS reduce 8->1
__global__ __launch_bounds__(256)
void fc_reduce_kernel(const float* __restrict__ P, const float* __restrict__ fcb,
                      float* __restrict__ out) {
    __shared__ float red[8][33];
    int o = blockIdx.x * 32 + (threadIdx.x & 31);
    int kg = threadIdx.x >> 5;
    float s = 0.f;
#pragma unroll
    for (int q = 0; q < 16; q++) s += P[(size_t)(kg * 16 + q) * 8192 + o];
    red[kg][threadIdx.x & 31] = s;
    __syncthreads();
    if (kg == 0) {
        float t = fcb[o & 511];
#pragma unroll
        for (int m = 0; m < 8; m++) t += red[m][threadIdx.x & 31];
        out[o] = 1.f / (1.f + expf(-t));
    }
}

// ---------------------------------------------------------------------------
extern "C" void kernel_launch(void* const* d_in, const int* in_sizes, int n_in,
                              void* d_out, int out_size, void* d_ws, size_t ws_size,
                              hipStream_t stream) {
    const float* V     = (const float*)d_in[0];
    const float* C     = (const float*)d_in[1];
    const float* gk_w0 = (const float*)d_in[2];
    const float* gk_b0 = (const float*)d_in[3];
    const float* ac_w0 = (const float*)d_in[4];
    const float* ac_b0 = (const float*)d_in[5];
    const float* gc_w0 = (const float*)d_in[6];
    const float* gc_b0 = (const float*)d_in[7];
    const float* bn_g0 = (const float*)d_in[8];
    const float* bn_b0 = (const float*)d_in[9];
    const float* gk_w1 = (const float*)d_in[10];
    const float* gk_b1 = (const float*)d_in[11];
    const float* ac_w1 = (const float*)d_in[12];
    const float* ac_b1 = (const float*)d_in[13];
    const float* gc_w1 = (const float*)d_in[14];
    const float* gc_b1 = (const float*)d_in[15];
    const float* bn_g1 = (const float*)d_in[16];
    const float* bn_b1 = (const float*)d_in[17];
    const float* fc_w  = (const float*)d_in[18];
    const float* fc_b  = (const float*)d_in[19];
    float* out = (float*)d_out;

    float* H0p = (float*)d_ws;        // [4096][128] = 524288 f32
    float* H1p = H0p + 524288;        // [2048][256] = 524288 f32
    float* P   = H1p + 524288;        // 128*16*512 = 1048576 f32
    u16* VT0 = (u16*)(P + 1048576);   // [16][64][512]  = 524288 u16
    u16* VT1 = VT0 + 524288;          // [16][128][256] = 524288 u16
    u16* Wt0 = VT1 + 524288;          // [128][576]  = 73728 u16
    u16* Wt1 = Wt0 + 73728;           // [256][1152] = 294912 u16

    prep_kernel<<<218, 256, 0, stream>>>(V, gc_w0, gc_w1, VT0, Wt0, Wt1);
    layer0_fused<<<512, 256, 0, stream>>>(VT0, C, V, gk_w0, gk_b0, ac_w0, ac_b0,
                                          Wt0, gc_b0, bn_g0, bn_b0, H0p, VT1);
    layer1_fused<<<512, 256, 0, stream>>>(VT1, C, H0p, gk_w1, gk_b1, ac_w1, ac_b1,
                                          Wt1, gc_b1, bn_g1, bn_b1, H1p);
    fc_partial_kernel<<<512, 256, 0, stream>>>(H1p, fc_w, P);
    fc_reduce_kernel<<<256, 256, 0, stream>>>(P, fc_b, out);
}

// Round 9
// 202.480 us; speedup vs baseline: 1.0855x; 1.0193x over previous
//
#include <hip/hip_runtime.h>
#include <math.h>

#define KK 8
#define EPSF 1e-9f

typedef unsigned int   uint32;
typedef unsigned short u16;
typedef __attribute__((ext_vector_type(8))) short bf16x8;
typedef __attribute__((ext_vector_type(4))) float f32x4;

#define MFMA_16x16x32(a, b, c) __builtin_amdgcn_mfma_f32_16x16x32_bf16(a, b, c, 0, 0, 0)

typedef __attribute__((address_space(1))) const unsigned int glob_cu32;
typedef __attribute__((address_space(3))) unsigned int lds_u32;
__device__ __forceinline__ void g2l16(const void* gsrc, void* ldst) {
    __builtin_amdgcn_global_load_lds((glob_cu32*)gsrc, (lds_u32*)ldst, 16, 0, 0);
}

// swizzled ushort index of logical octet o (8 bf16) in a [row][64] LDS tile
__device__ __forceinline__ int swz(int row, int o) {
    return (row << 6) + (((o) ^ (row & 7)) << 3);
}

__device__ __forceinline__ float softplusf(float x) {
    return x > 0.0f ? x + log1pf(expf(-x)) : log1pf(expf(x));
}
__device__ __forceinline__ float sigmoidf_(float x) {
    return 1.0f / (1.0f + expf(-x));
}
__device__ __forceinline__ u16 f2bf(float f) {
    union { float f; uint32 u; } v; v.f = f;
    uint32 u = v.u;
    return (u16)((u + 0x7FFFu + ((u >> 16) & 1u)) >> 16);
}
__device__ __forceinline__ uint32 pack2(float a, float b) {
    return (uint32)f2bf(a) | ((uint32)f2bf(b) << 16);
}

// ---------------------------------------------------------------------------
// prep: V->VT0 bf16 [16][64][512] (transposed), gc_w0->Wt0 bf16 [128][576],
//       gc_w1->Wt1 bf16 [256][1152].
// ---------------------------------------------------------------------------
__global__ __launch_bounds__(256)
void prep_kernel(const float* __restrict__ V, const float* __restrict__ W0,
                 const float* __restrict__ W1, u16* __restrict__ VT0,
                 u16* __restrict__ Wt0, u16* __restrict__ Wt1) {
    __shared__ float s[64][65];
    int blk = blockIdx.x, tid = threadIdx.x;
    if (blk < 128) {            // V [16][512][64] -> VT0 [16][64][512]
        int b = blk >> 3, rt = blk & 7;
#pragma unroll
        for (int t = 0; t < 16; t++) {
            int idx = t * 256 + tid; int r = idx >> 6, c = idx & 63;
            s[r][c] = V[((size_t)b * 512 + rt * 64 + r) * 64 + c];
        }
        __syncthreads();
#pragma unroll
        for (int t = 0; t < 16; t++) {
            int idx = t * 256 + tid; int f = idx >> 6, j = idx & 63;
            VT0[((size_t)b * 64 + f) * 512 + rt * 64 + j] = f2bf(s[j][f]);
        }
    } else if (blk < 146) {     // W0 [576][128] -> Wt0 [128][576]
        int t0 = blk - 128; int rt = t0 >> 1, ct = t0 & 1;
#pragma unroll
        for (int t = 0; t < 16; t++) {
            int idx = t * 256 + tid; int r = idx >> 6, c = idx & 63;
            s[r][c] = W0[((size_t)rt * 64 + r) * 128 + ct * 64 + c];
        }
        __syncthreads();
#pragma unroll
        for (int t = 0; t < 16; t++) {
            int idx = t * 256 + tid; int f = idx >> 6, j = idx & 63;
            Wt0[((size_t)ct * 64 + f) * 576 + rt * 64 + j] = f2bf(s[j][f]);
        }
    } else {                    // W1 [1152][256] -> Wt1 [256][1152]
        int t0 = blk - 146; int rt = t0 >> 2, ct = t0 & 3;
#pragma unroll
        for (int t = 0; t < 16; t++) {
            int idx = t * 256 + tid; int r = idx >> 6, c = idx & 63;
            s[r][c] = W1[((size_t)rt * 64 + r) * 256 + ct * 64 + c];
        }
        __syncthreads();
#pragma unroll
        for (int t = 0; t < 16; t++) {
            int idx = t * 256 + tid; int f = idx >> 6, j = idx & 63;
            Wt1[((size_t)ct * 64 + f) * 1152 + rt * 64 + j] = f2bf(s[j][f]);
        }
    }
}

// ---------------------------------------------------------------------------
// layer0_fused v2: 512 threads, 32 node-rows/block. Grid 256 = 16 b x 16 tiles.
// Phase B: dbuf (s_vT+s_A), 1 barrier/iter, A-gen(n+1) overlaps MFMA(n).
// Phase D: dbuf W chunks [128c x 64k]. LDS ~119 KB.
// ---------------------------------------------------------------------------
__global__ __launch_bounds__(512)
void layer0_fused(const u16* __restrict__ VT0, const float* __restrict__ C,
                  const float* __restrict__ V,
                  const float* __restrict__ gw, const float* __restrict__ gb,
                  const float* __restrict__ aw, const float* __restrict__ ab,
                  const u16* __restrict__ Wt0, const float* __restrict__ bias,
                  const float* __restrict__ bng, const float* __restrict__ bnb,
                  float* __restrict__ H0p, u16* __restrict__ VT1) {
    int b = blockIdx.x >> 4, tile = blockIdx.x & 15;
    int i0 = tile * 32;
    int tid = threadIdx.x;
    int wv = tid >> 6, lane = tid & 63, quad = lane >> 4, l15 = lane & 15;

    // dbuf: each buf = s_vT 4096 u16 (8KB) + s_A 16384 u16 (32KB)
    __shared__ __align__(16) u16 s_mem[2][20480];    // 80 KB
    __shared__ __align__(16) u16 s_X[32 * 584];      // 36.5 KB
    __shared__ __align__(16) float s_ci[32][4];
    __shared__ float s_u[32][KK];
    __shared__ float s_w[32][KK];

    // ---- phase A ----
    {
        int t = tid & 255;
        int i = t >> 3, k = t & 7;
        const float4* xr = (const float4*)(V + ((size_t)b * 512 + i0 + i) * 64);
        const float* wm = (tid < 256) ? gw : aw;
        float s = 0.f;
#pragma unroll
        for (int f4 = 0; f4 < 16; f4++) {
            float4 x = xr[f4];
            s += x.x * wm[(f4 * 4 + 0) * 8 + k] + x.y * wm[(f4 * 4 + 1) * 8 + k]
               + x.z * wm[(f4 * 4 + 2) * 8 + k] + x.w * wm[(f4 * 4 + 3) * 8 + k];
        }
        if (tid < 256) s_u[i][k] = softplusf(s + gb[k]);
        else           s_w[i][k] = sigmoidf_(s + ab[k]);
    }
    if (tid < 32) {
        const float* cp = C + ((size_t)b * 512 + i0 + tid) * 3;
        float x = cp[0], y = cp[1], z = cp[2];
        s_ci[tid][0] = x; s_ci[tid][1] = y; s_ci[tid][2] = z;
        s_ci[tid][3] = x * x + y * y + z * z;
    }
    {   // V rows -> s_X cols 0..63 (bf16): 32 rows x 16 f4 = 512 threads
        int row = tid >> 4, f4 = tid & 15;
        float4 x = *(const float4*)(V + ((size_t)b * 512 + i0 + row) * 64 + f4 * 4);
        *(uint32*)&s_X[row * 584 + f4 * 4]     = pack2(x.x, x.y);
        *(uint32*)&s_X[row * 584 + f4 * 4 + 2] = pack2(x.z, x.w);
    }

    int ia = tid >> 4, jg = tid & 15;            // A-gen: i 0..31, 4-j group
    int oct = jg >> 1, half = (jg & 1) << 2;

    auto dmaV = [&](int j0, u16* sV) {
        int s = wv * 64 + lane;                  // 512 slots = 64 f x 8 oct
        int f = s >> 3, op = s & 7;
        g2l16(VT0 + ((size_t)b * 64 + f) * 512 + j0 + ((op ^ (f & 7)) << 3),
              (void*)(sV + (wv * 64) * 8));
    };
    auto agen = [&](float4 q0, float4 q1, float4 q2, u16* sA) {
        float jx[4] = {q0.x, q0.w, q1.z, q2.y};
        float jy[4] = {q0.y, q1.x, q1.w, q2.z};
        float jz[4] = {q0.z, q1.y, q2.x, q2.w};
        float cix = s_ci[ia][0], ciy = s_ci[ia][1], ciz = s_ci[ia][2], l2i = s_ci[ia][3];
        float d2a[4], csa[4];
#pragma unroll
        for (int jj = 0; jj < 4; jj++) {
            float l2j = jx[jj] * jx[jj] + jy[jj] * jy[jj] + jz[jj] * jz[jj];
            float dot = cix * jx[jj] + ciy * jy[jj] + ciz * jz[jj];
            d2a[jj] = fabsf(l2i + l2j - 2.f * dot) + EPSF;
            csa[jj] = dot / sqrtf((l2i + EPSF) * (l2j + EPSF));
        }
        const float* up = &s_u[ia][0];
        const float* wp = &s_w[ia][0];
#pragma unroll
        for (int k = 0; k < 8; k++) {
            float uu = up[k], ww = wp[k], om = 1.f - ww;
            float a0 = __expf(-d2a[0] * uu) * (ww * csa[0] + om);
            float a1 = __expf(-d2a[1] * uu) * (ww * csa[1] + om);
            float a2 = __expf(-d2a[2] * uu) * (ww * csa[2] + om);
            float a3 = __expf(-d2a[3] * uu) * (ww * csa[3] + om);
            int row = ia * 8 + k;
            uint2 pk = make_uint2(pack2(a0, a1), pack2(a2, a3));
            *(uint2*)&sA[(row << 6) + ((oct ^ (row & 7)) << 3) + half] = pk;
        }
    };

    __syncthreads();                 // phase A visible

    // ---- phase B: pipelined j-loop (8 iters, 1 barrier each) ----
    f32x4 acc[2][4] = {};
    {
        const float4* cp4 = (const float4*)(C + ((size_t)b * 512 + 0 + jg * 4) * 3);
        float4 q0 = cp4[0], q1 = cp4[1], q2 = cp4[2];
        agen(q0, q1, q2, s_mem[0] + 4096);
        dmaV(0, s_mem[0]);
    }
    for (int n = 0; n < 8; n++) {
        float4 q0, q1, q2;
        if (n < 7) {                 // prefetch next coords before barrier
            const float4* cp4 = (const float4*)(C + ((size_t)b * 512 + (n + 1) * 64 + jg * 4) * 3);
            q0 = cp4[0]; q1 = cp4[1]; q2 = cp4[2];
        }
        __syncthreads();             // drains DMA(n); A(n) visible; reads(n-1) done
        if (n < 7) {
            dmaV((n + 1) * 64, s_mem[(n + 1) & 1]);
            agen(q0, q1, q2, s_mem[(n + 1) & 1] + 4096);
        }
        const u16* sV = s_mem[n & 1];
        const u16* sA = s_mem[n & 1] + 4096;
#pragma unroll
        for (int ks = 0; ks < 2; ks++) {
            int o = ks * 4 + quad;
            bf16x8 a0 = *(const bf16x8*)&sA[swz(wv * 32 + l15, o)];
            bf16x8 a1 = *(const bf16x8*)&sA[swz(wv * 32 + 16 + l15, o)];
#pragma unroll
            for (int cf = 0; cf < 4; cf++) {
                bf16x8 bv = *(const bf16x8*)&sV[swz(cf * 16 + l15, o)];
                acc[0][cf] = MFMA_16x16x32(a0, bv, acc[0][cf]);
                acc[1][cf] = MFMA_16x16x32(a1, bv, acc[1][cf]);
            }
        }
    }

    // ---- phase C: msg acc -> s_X cols 64..575 ----
#pragma unroll
    for (int rf = 0; rf < 2; rf++)
#pragma unroll
        for (int cf = 0; cf < 4; cf++)
#pragma unroll
            for (int r = 0; r < 4; r++) {
                int arow = wv * 32 + rf * 16 + quad * 4 + r;
                int i = arow >> 3, k = arow & 7;
                s_X[i * 584 + 64 + k * 64 + cf * 16 + l15] = f2bf(acc[rf][cf][r]);
            }
    __syncthreads();                 // s_X ready; s_mem free

    // ---- phase D: dbuf mini-GEMM [32 x 576] @ Wt0^T, 9 chunks [128c x 64k] ----
    u16* wbuf0 = s_mem[0];
    u16* wbuf1 = s_mem[0] + 8192;    // 2 x 16 KB within buffer 0 region
    auto dmaW0 = [&](int kc, u16* buf) {
#pragma unroll
        for (int p = 0; p < 2; p++) {
            int s = p * 512 + tid;
            int cc = s >> 3, op = s & 7;
            g2l16(Wt0 + (size_t)cc * 576 + kc + ((op ^ (cc & 7)) << 3),
                  (void*)(buf + (p * 512 + wv * 64) * 8));
        }
    };
    dmaW0(0, wbuf0);
    f32x4 acc2[2] = {};
    int rw = wv & 1, cw = wv >> 1;   // rowfrag 0..1, colgroup 0..3
    for (int c = 0; c < 9; c++) {
        u16* cur = (c & 1) ? wbuf1 : wbuf0;
        u16* nxt = (c & 1) ? wbuf0 : wbuf1;
        __syncthreads();
        if (c < 8) dmaW0((c + 1) * 64, nxt);
        int kc = c * 64;
#pragma unroll
        for (int ks = 0; ks < 2; ks++) {
            int o = ks * 4 + quad;
            bf16x8 av = *(const bf16x8*)&s_X[(rw * 16 + l15) * 584 + kc + o * 8];
#pragma unroll
            for (int cf = 0; cf < 2; cf++) {
                bf16x8 bv = *(const bf16x8*)&cur[swz(cw * 32 + cf * 16 + l15, o)];
                acc2[cf] = MFMA_16x16x32(av, bv, acc2[cf]);
            }
        }
    }

    // ---- phase E: tanh/bn/pool -> H0p + transposed VT1 ----
#pragma unroll
    for (int cf = 0; cf < 2; cf++) {
        int col = cw * 32 + cf * 16 + l15;
        float bs = bias[col], gg = bng[col], bb = bnb[col];
        float h0 = gg * tanhf(acc2[cf][0] + bs) + bb;
        float h1 = gg * tanhf(acc2[cf][1] + bs) + bb;
        float h2 = gg * tanhf(acc2[cf][2] + bs) + bb;
        float h3 = gg * tanhf(acc2[cf][3] + bs) + bb;
        float p0 = 0.5f * (h0 + h1), p1 = 0.5f * (h2 + h3);
        int pl = tile * 16 + rw * 8 + quad * 2;      // pooled row in b (0..255)
        H0p[((size_t)b * 256 + pl) * 128 + col] = p0;
        H0p[((size_t)b * 256 + pl + 1) * 128 + col] = p1;
        VT1[((size_t)b * 128 + col) * 256 + pl]     = f2bf(p0);
        VT1[((size_t)b * 128 + col) * 256 + pl + 1] = f2bf(p1);
    }
}

// ---------------------------------------------------------------------------
// layer1_fused v2: 512 threads, 16 pooled-rows/block. Grid 256 = 16 b x 16 tiles.
// Phase B: dbuf, 1 barrier/iter. Phase D: [256c x 64k] chunks, 16 valid A-rows
// (no dup waste), W staged once per 16 rows. LDS ~104 KB.
// ---------------------------------------------------------------------------
__global__ __launch_bounds__(512)
void layer1_fused(const u16* __restrict__ VT1, const float* __restrict__ C,
                  const float* __restrict__ H0p,
                  const float* __restrict__ gw, const float* __restrict__ gb,
                  const float* __restrict__ aw, const float* __restrict__ ab,
                  const u16* __restrict__ Wt1, const float* __restrict__ bias,
                  const float* __restrict__ bng, const float* __restrict__ bnb,
                  float* __restrict__ H1p) {
    int b = blockIdx.x >> 4, tile = blockIdx.x & 15;
    int i0 = tile * 16;
    int tid = threadIdx.x;
    int wv = tid >> 6, lane = tid & 63, quad = lane >> 4, l15 = lane & 15;

    // dbuf: each buf = s_vT 8192 u16 + s_A 8192 u16 = 32 KB; phase D: 2 x 32 KB
    __shared__ __align__(16) u16 s_mem[2][16384];    // 64 KB
    __shared__ __align__(16) u16 s_X1[16 * 1160];    // 36.3 KB
    __shared__ __align__(16) float s_ci[16][4];
    __shared__ float s_u[16][KK];
    __shared__ float s_w[16][KK];

    // ---- phase A ----
    if (tid < 256) {   // uw over H0p rows (F=128)
        int t = tid & 127;
        int i = t >> 3, k = t & 7;
        const float4* xr = (const float4*)(H0p + ((size_t)b * 256 + i0 + i) * 128);
        const float* wm = (tid < 128) ? gw : aw;
        float s = 0.f;
#pragma unroll
        for (int f4 = 0; f4 < 32; f4++) {
            float4 x = xr[f4];
            s += x.x * wm[(f4 * 4 + 0) * 8 + k] + x.y * wm[(f4 * 4 + 1) * 8 + k]
               + x.z * wm[(f4 * 4 + 2) * 8 + k] + x.w * wm[(f4 * 4 + 3) * 8 + k];
        }
        if (tid < 128) s_u[i][k] = softplusf(s + gb[k]);
        else           s_w[i][k] = sigmoidf_(s + ab[k]);
    }
    if (tid < 16) {    // pooled coords
        const float* cp = C + ((size_t)b * 512 + 2 * (i0 + tid)) * 3;
        float x = 0.5f * (cp[0] + cp[3]);
        float y = 0.5f * (cp[1] + cp[4]);
        float z = 0.5f * (cp[2] + cp[5]);
        s_ci[tid][0] = x; s_ci[tid][1] = y; s_ci[tid][2] = z;
        s_ci[tid][3] = x * x + y * y + z * z;
    }
    {   // H0p rows -> s_X1 cols 0..127: 16 rows x 32 f4 = 512 threads
        int row = tid >> 5, f4 = tid & 31;
        float4 x = *(const float4*)(H0p + ((size_t)b * 256 + i0 + row) * 128 + f4 * 4);
        *(uint32*)&s_X1[row * 1160 + f4 * 4]     = pack2(x.x, x.y);
        *(uint32*)&s_X1[row * 1160 + f4 * 4 + 2] = pack2(x.z, x.w);
    }

    int kh = tid >> 8, ia = (tid >> 4) & 15, jg = tid & 15;  // A-gen: 4j x 4k
    int oct = jg >> 1, half = (jg & 1) << 2;

    auto dmaV = [&](int j0, u16* sV) {
#pragma unroll
        for (int p = 0; p < 2; p++) {            // 128 f x 8 oct = 1024 slots
            int s = p * 512 + tid;
            int f = s >> 3, op = s & 7;
            g2l16(VT1 + ((size_t)b * 128 + f) * 256 + j0 + ((op ^ (f & 7)) << 3),
                  (void*)(sV + (p * 512 + wv * 64) * 8));
        }
    };
    auto agen = [&](const float* r, u16* sA) {
        float jx[4], jy[4], jz[4];
#pragma unroll
        for (int jj = 0; jj < 4; jj++) {
            jx[jj] = 0.5f * (r[6 * jj] + r[6 * jj + 3]);
            jy[jj] = 0.5f * (r[6 * jj + 1] + r[6 * jj + 4]);
            jz[jj] = 0.5f * (r[6 * jj + 2] + r[6 * jj + 5]);
        }
        float cix = s_ci[ia][0], ciy = s_ci[ia][1], ciz = s_ci[ia][2], l2i = s_ci[ia][3];
        float d2a[4], csa[4];
#pragma unroll
        for (int jj = 0; jj < 4; jj++) {
            float l2j = jx[jj] * jx[jj] + jy[jj] * jy[jj] + jz[jj] * jz[jj];
            float dot = cix * jx[jj] + ciy * jy[jj] + ciz * jz[jj];
            d2a[jj] = fabsf(l2i + l2j - 2.f * dot) + EPSF;
            csa[jj] = dot / sqrtf((l2i + EPSF) * (l2j + EPSF));
        }
        const float* up = &s_u[ia][kh * 4];
        const float* wp = &s_w[ia][kh * 4];
#pragma unroll
        for (int kk = 0; kk < 4; kk++) {
            float uu = up[kk], ww = wp[kk], om = 1.f - ww;
            float a0 = __expf(-d2a[0] * uu) * (ww * csa[0] + om);
            float a1 = __expf(-d2a[1] * uu) * (ww * csa[1] + om);
            float a2 = __expf(-d2a[2] * uu) * (ww * csa[2] + om);
            float a3 = __expf(-d2a[3] * uu) * (ww * csa[3] + om);
            int row = ia * 8 + kh * 4 + kk;
            uint2 pk = make_uint2(pack2(a0, a1), pack2(a2, a3));
            *(uint2*)&sA[(row << 6) + ((oct ^ (row & 7)) << 3) + half] = pk;
        }
    };

    __syncthreads();

    // ---- phase B: pipelined j-loop (4 iters) ----
    f32x4 acc[8] = {};
    {
        const float4* cp4 = (const float4*)(C + ((size_t)b * 512 + 2 * (0 + jg * 4)) * 3);
        float4 q[6]; for (int z = 0; z < 6; z++) q[z] = cp4[z];
        agen((const float*)q, s_mem[0] + 8192);
        dmaV(0, s_mem[0]);
    }
    for (int n = 0; n < 4; n++) {
        float4 q[6];
        if (n < 3) {
            const float4* cp4 = (const float4*)(C + ((size_t)b * 512 + 2 * ((n + 1) * 64 + jg * 4)) * 3);
#pragma unroll
            for (int z = 0; z < 6; z++) q[z] = cp4[z];
        }
        __syncthreads();
        if (n < 3) {
            dmaV((n + 1) * 64, s_mem[(n + 1) & 1]);
            agen((const float*)q, s_mem[(n + 1) & 1] + 8192);
        }
        const u16* sV = s_mem[n & 1];
        const u16* sA = s_mem[n & 1] + 8192;
#pragma unroll
        for (int ks = 0; ks < 2; ks++) {
            int o = ks * 4 + quad;
            bf16x8 a0 = *(const bf16x8*)&sA[swz(wv * 16 + l15, o)];
#pragma unroll
            for (int cf = 0; cf < 8; cf++) {
                bf16x8 bv = *(const bf16x8*)&sV[swz(cf * 16 + l15, o)];
                acc[cf] = MFMA_16x16x32(a0, bv, acc[cf]);
            }
        }
    }

    // ---- phase C: msg acc -> s_X1 cols 128..1151 ----
#pragma unroll
    for (int cf = 0; cf < 8; cf++)
#pragma unroll
        for (int r = 0; r < 4; r++) {
            int arow = wv * 16 + quad * 4 + r;
            int i = arow >> 3, k = arow & 7;
            s_X1[i * 1160 + 128 + k * 128 + cf * 16 + l15] = f2bf(acc[cf][r]);
        }
    __syncthreads();

    // ---- phase D: dbuf mini-GEMM [16 x 1152] @ Wt1^T, 18 chunks [256c x 64k] ----
    auto dmaW1 = [&](int kc, u16* buf) {
#pragma unroll
        for (int p = 0; p < 4; p++) {            // 256 c x 8 oct = 2048 slots
            int s = p * 512 + tid;
            int cc = s >> 3, op = s & 7;
            g2l16(Wt1 + (size_t)cc * 1152 + kc + ((op ^ (cc & 7)) << 3),
                  (void*)(buf + (p * 512 + wv * 64) * 8));
        }
    };
    dmaW1(0, s_mem[0]);
    f32x4 acc2[2] = {};
    for (int c = 0; c < 18; c++) {
        u16* cur = s_mem[c & 1];
        u16* nxt = s_mem[(c + 1) & 1];
        __syncthreads();
        if (c < 17) dmaW1((c + 1) * 64, nxt);
        int kc = c * 64;
#pragma unroll
        for (int ks = 0; ks < 2; ks++) {
            int o = ks * 4 + quad;
            bf16x8 av = *(const bf16x8*)&s_X1[l15 * 1160 + kc + o * 8];
#pragma unroll
            for (int cf = 0; cf < 2; cf++) {
                bf16x8 bv = *(const bf16x8*)&cur[swz(wv * 32 + cf * 16 + l15, o)];
                acc2[cf] = MFMA_16x16x32(av, bv, acc2[cf]);
            }
        }
    }

    // ---- phase E: tanh/bn/pool -> H1p (all rows valid) ----
#pragma unroll
    for (int cf = 0; cf < 2; cf++) {
        int col = wv * 32 + cf * 16 + l15;
        float bs = bias[col], gg = bng[col], bb = bnb[col];
        float h0 = gg * tanhf(acc2[cf][0] + bs) + bb;
        float h1 = gg * tanhf(acc2[cf][1] + bs) + bb;
        float h2 = gg * tanhf(acc2[cf][2] + bs) + bb;
        float h3 = gg * tanhf(acc2[cf][3] + bs) + bb;
        float p0 = 0.5f * (h0 + h1), p1 = 0.5f * (h2 + h3);
        int pl = tile * 8 + quad * 2;            // pooled row in b (0..127)
        H1p[((size_t)b * 128 + pl) * 256 + col] = p0;
        H1p[((size_t)b * 128 + pl + 1) * 256 + col] = p1;
    }
}

// ---------------------------------------------------------------------------
// FC split-K: grid 512 = 4 col-splits x 128 k-splits (m-chunks of 256).
// ---------------------------------------------------------------------------
__global__ __launch_bounds__(256)
void fc_partial_kernel(const float* __restrict__ Flat, const float* __restrict__ W,
                       float* __restrict__ P) {
    int cs = blockIdx.x & 3, ks = blockIdx.x >> 2;
    int m0 = ks * 256;
    int c4 = threadIdx.x & 31;
    int msub = threadIdx.x >> 5;

    __shared__ __align__(16) float xT[256][16];

#pragma unroll
    for (int q = 0; q < 16; q++) {
        int idx = q * 256 + threadIdx.x;
        int b = idx >> 8, mm = idx & 255;
        int bg = (b >> 2) ^ (mm & 3);
        xT[mm][(bg << 2) + (b & 3)] = Flat[(size_t)b * 32768 + m0 + mm];
    }
    __syncthreads();

    const float4* W4 = (const float4*)W;
    float4 acc[16] = {};

    for (int h = 0; h < 4; h++) {
        float4 wbuf[8];
#pragma unroll
        for (int i = 0; i < 8; i++) {
            int mm = msub * 32 + h * 8 + i;
            wbuf[i] = W4[(size_t)(m0 + mm) * 128 + cs * 32 + c4];
        }
#pragma unroll
        for (int i = 0; i < 8; i++) {
            int mm = msub * 32 + h * 8 + i;
#pragma unroll
            for (int bg = 0; bg < 4; bg++) {
                float4 xv = *(const float4*)&xT[mm][((bg ^ (mm & 3)) << 2)];
                acc[bg * 4 + 0].x += xv.x * wbuf[i].x; acc[bg * 4 + 0].y += xv.x * wbuf[i].y;
                acc[bg * 4 + 0].z += xv.x * wbuf[i].z; acc[bg * 4 + 0].w += xv.x * wbuf[i].w;
                acc[bg * 4 + 1].x += xv.y * wbuf[i].x; acc[bg * 4 + 1].y += xv.y * wbuf[i].y;
                acc[bg * 4 + 1].z += xv.y * wbuf[i].z; acc[bg * 4 + 1].w += xv.y * wbuf[i].w;
                acc[bg * 4 + 2].x += xv.z * wbuf[i].x; acc[bg * 4 + 2].y += xv.z * wbuf[i].y;
                acc[bg * 4 + 2].z += xv.z * wbuf[i].z; acc[bg * 4 + 2].w += xv.z * wbuf[i].w;
                acc[bg * 4 + 3].x += xv.w * wbuf[i].x; acc[bg * 4 + 3].y += xv.w * wbuf[i].y;
                acc[bg * 4 + 3].z += xv.w * wbuf[i].z; acc[bg * 4 + 3].w += xv.w * wbuf[i].w;
            }
        }
    }
    __syncthreads();
    __shared__ __align__(16) float red[8][32][4];
#pragma unroll
    for (int b = 0; b < 16; b++) {
        red[msub][c4][0] = acc[b].x; red[msub][c4][1] = acc[b].y;
        red[msub][c4][2] = acc[b].z; red[msub][c4][3] = acc[b].w;
        __syncthreads();
        if (msub == 0) {
            float4 s = make_float4(0.f, 0.f, 0.f, 0.f);
#pragma unroll
            for (int m = 0; m < 8; m++) {
                s.x += red[m][c4][0]; s.y += red[m][c4][1];
                s.z += red[m][c4][2]; s.w += red[m][c4][3];
            }
            *(float4*)&P[((size_t)ks * 16 + b) * 512 + cs * 128 + c4 * 4] = s;
        }
        __syncthreads();
    }
}

// grid 256: block = 32 outputs; thread (o, kg) sums 16 ks; LDS reduce 8->1
__global__ __launch_bounds__(256)
void fc_reduce_kernel(const float* __restrict__ P, const float* __restrict__ fcb,
                      float* __restrict__ out) {
    __shared__ float red[8][33];
    int o = blockIdx.x * 32 + (threadIdx.x & 31);
    int kg = threadIdx.x >> 5;
    float s = 0.f;
#pragma unroll
    for (int q = 0; q < 16; q++) s += P[(size_t)(kg * 16 + q) * 8192 + o];
    red[kg][threadIdx.x & 31] = s;
    __syncthreads();
    if (kg == 0) {
        float t = fcb[o & 511];
#pragma unroll
        for (int m = 0; m < 8; m++) t += red[m][threadIdx.x & 31];
        out[o] = 1.f / (1.f + expf(-t));
    }
}

// ---------------------------------------------------------------------------
extern "C" void kernel_launch(void* const* d_in, const int* in_sizes, int n_in,
                              void* d_out, int out_size, void* d_ws, size_t ws_size,
                              hipStream_t stream) {
    const float* V     = (const float*)d_in[0];
    const float* C     = (const float*)d_in[1];
    const float* gk_w0 = (const float*)d_in[2];
    const float* gk_b0 = (const float*)d_in[3];
    const float* ac_w0 = (const float*)d_in[4];
    const float* ac_b0 = (const float*)d_in[5];
    const float* gc_w0 = (const float*)d_in[6];
    const float* gc_b0 = (const float*)d_in[7];
    const float* bn_g0 = (const float*)d_in[8];
    const float* bn_b0 = (const float*)d_in[9];
    const float* gk_w1 = (const float*)d_in[10];
    const float* gk_b1 = (const float*)d_in[11];
    const float* ac_w1 = (const float*)d_in[12];
    const float* ac_b1 = (const float*)d_in[13];
    const float* gc_w1 = (const float*)d_in[14];
    const float* gc_b1 = (const float*)d_in[15];
    const float* bn_g1 = (const float*)d_in[16];
    const float* bn_b1 = (const float*)d_in[17];
    const float* fc_w  = (const float*)d_in[18];
    const float* fc_b  = (const float*)d_in[19];
    float* out = (float*)d_out;

    float* H0p = (float*)d_ws;        // [4096][128] = 524288 f32
    float* H1p = H0p + 524288;        // [2048][256] = 524288 f32
    float* P   = H1p + 524288;        // 128*16*512 = 1048576 f32
    u16* VT0 = (u16*)(P + 1048576);   // [16][64][512]  = 524288 u16
    u16* VT1 = VT0 + 524288;          // [16][128][256] = 524288 u16
    u16* Wt0 = VT1 + 524288;          // [128][576]  = 73728 u16
    u16* Wt1 = Wt0 + 73728;           // [256][1152] = 294912 u16

    prep_kernel<<<218, 256, 0, stream>>>(V, gc_w0, gc_w1, VT0, Wt0, Wt1);
    layer0_fused<<<256, 512, 0, stream>>>(VT0, C, V, gk_w0, gk_b0, ac_w0, ac_b0,
                                          Wt0, gc_b0, bn_g0, bn_b0, H0p, VT1);
    layer1_fused<<<256, 512, 0, stream>>>(VT1, C, H0p, gk_w1, gk_b1, ac_w1, ac_b1,
                                          Wt1, gc_b1, bn_g1, bn_b1, H1p);
    fc_partial_kernel<<<512, 256, 0, stream>>>(H1p, fc_w, P);
    fc_reduce_kernel<<<256, 256, 0, stream>>>(P, fc_b, out);
}